// Round 4
// baseline (224.844 us; speedup 1.0000x reference)
//
#include <hip/hip_runtime.h>
#include <math.h>

#define VOCAB 32000
#define D 768
#define S 512
#define W 300
#define B 64
#define LMAX 4

typedef float f32x4 __attribute__((ext_vector_type(4)));

// ---------------------------------------------------------------------------
// Kernel 1: prep. Per batch: first-break scan + fill id, then emit one 16B
// descriptor per word so the hot kernel's prologue is a single scalar load.
//   mode 0 (copy-emb):   out = emb[d.x]            (fill path / en >= S)
//   mode 2 (copy-ernie): out = ernie_row[d.x]      (pool with span_eff == 1:
//                        softmax over a singleton is exactly 1.0, so the
//                        pooled output IS the char row — bit-exact vs ref)
//   mode 1 (pool):       softmax-pool, d = {wid, b*S+p0, span_eff, 1}
// ---------------------------------------------------------------------------
__global__ __launch_bounds__(64) void prep_kernel(
    const int* __restrict__ word_index,  // (B, W, 3)
    int4* __restrict__ desc)             // (B, W)
{
    const int b = blockIdx.x;
    const int lane = threadIdx.x;  // 0..63

    int my_first = W;
    for (int w = lane; w < W; w += 64) {
        const int base = (b * W + w) * 3;
        const int st = word_index[base + 1];
        const int en = word_index[base + 2];
        if (en < S && en <= st) my_first = min(my_first, w);
    }
    #pragma unroll
    for (int off = 32; off > 0; off >>= 1)
        my_first = min(my_first, __shfl_xor(my_first, off));
    const int first = my_first;  // butterfly -> all lanes hold the min

    const int fw = min(first, W - 1);
    const int fillid = word_index[(b * W + fw) * 3 + 0];  // same addr all lanes

    for (int w = lane; w < W; w += 64) {
        const int base = (b * W + w) * 3;
        const int wid = word_index[base + 0];
        const int st  = word_index[base + 1];
        const int en  = word_index[base + 2];
        int4 d;
        if (w >= first) {
            d.x = fillid; d.y = 0; d.z = 0; d.w = 0;
        } else if (en >= S) {
            d.x = wid; d.y = 0; d.z = 0; d.w = 0;
        } else {
            const int p0 = min(max(st, 0), S - 1);
            const int span = min(max(en - st, 1), LMAX);
            if (span == 1) {
                d.x = b * S + p0; d.y = 0; d.z = 0; d.w = 2;
            } else {
                d.x = wid;
                d.y = b * S + p0;   // global ernie row of first char
                d.z = span;         // 2..LMAX
                d.w = 1;
            }
        }
        desc[b * W + w] = d;
    }
}

// ---------------------------------------------------------------------------
// Kernel 2: one wave per word. Single scalar-load prologue (descriptor).
// Copy modes (emb row or ernie row) are pure row copies. Pool mode
// (span >= 2) issues all rows up-front (one latency epoch), flat softmax:
// independent dots -> one batched butterfly -> in-lane softmax -> weighted
// sum. Loads are cacheable (L3 retains ernie/emb across bench iterations);
// stores are nontemporal (out is write-only).
// ---------------------------------------------------------------------------
__global__ __launch_bounds__(256) void pool_kernel(
    const float* __restrict__ ernie,   // (B, S, D)
    const float* __restrict__ emb,     // (VOCAB, D)
    const int4* __restrict__ desc,     // (B, W)
    float* __restrict__ out)           // (B, W, D)
{
    int gw = (int)((blockIdx.x * blockDim.x + threadIdx.x) >> 6);
    gw = __builtin_amdgcn_readfirstlane(gw);  // wave-uniform -> SGPR
    const int lane = threadIdx.x & 63;

    const int4 d = desc[gw];  // uniform address -> scalar load

    f32x4* __restrict__ outp = (f32x4*)out + (size_t)gw * 192;

    if (d.w != 1) {  // ---- copy paths: emb row (mode 0) or ernie row (mode 2)
        const float* srcbase = (d.w == 2) ? ernie : emb;
        const f32x4* __restrict__ src = (const f32x4*)srcbase + (size_t)d.x * 192;
        __builtin_nontemporal_store(src[lane],       &outp[lane]);
        __builtin_nontemporal_store(src[lane + 64],  &outp[lane + 64]);
        __builtin_nontemporal_store(src[lane + 128], &outp[lane + 128]);
        return;
    }

    // ---- pooling path (span 2..4) ----
    const int span = d.z;  // wave-uniform (SGPR) -> scalar branches
    const f32x4* __restrict__ rp = (const f32x4*)emb + (size_t)d.x * 192;
    const f32x4* __restrict__ cb = (const f32x4*)ernie + (size_t)d.y * 192;

    // Issue everything up-front: one memory-latency epoch.
    f32x4 we0 = rp[lane], we1 = rp[lane + 64], we2 = rp[lane + 128];

    f32x4 c[LMAX][3];  // statically indexed everywhere (no scratch)
    c[0][0] = cb[lane];
    c[0][1] = cb[lane + 64];
    c[0][2] = cb[lane + 128];
    c[1][0] = cb[192 + lane];
    c[1][1] = cb[192 + lane + 64];
    c[1][2] = cb[192 + lane + 128];
    if (span > 2) {
        c[2][0] = cb[384 + lane];
        c[2][1] = cb[384 + lane + 64];
        c[2][2] = cb[384 + lane + 128];
    }
    if (span > 3) {
        c[3][0] = cb[576 + lane];
        c[3][1] = cb[576 + lane + 64];
        c[3][2] = cb[576 + lane + 128];
    }

    // Per-lane partial dots (independent). Inactive slots get -inf so
    // exp() yields exactly 0 (-inf is butterfly-safe: -inf + -inf = -inf).
    f32x4 pv0 = c[0][0] * we0 + c[0][1] * we1 + c[0][2] * we2;
    f32x4 pv1 = c[1][0] * we0 + c[1][1] * we1 + c[1][2] * we2;
    float s0 = pv0.x + pv0.y + pv0.z + pv0.w;
    float s1 = pv1.x + pv1.y + pv1.z + pv1.w;
    float s2 = -INFINITY, s3 = -INFINITY;
    if (span > 2) {
        f32x4 pv = c[2][0] * we0 + c[2][1] * we1 + c[2][2] * we2;
        s2 = pv.x + pv.y + pv.z + pv.w;
    }
    if (span > 3) {
        f32x4 pv = c[3][0] * we0 + c[3][1] * we1 + c[3][2] * we2;
        s3 = pv.x + pv.y + pv.z + pv.w;
    }

    // Batched butterfly: only the live chains (span is scalar -> no diverge).
    if (span == 2) {
        #pragma unroll
        for (int off = 32; off > 0; off >>= 1) {
            s0 += __shfl_xor(s0, off);
            s1 += __shfl_xor(s1, off);
        }
    } else {
        #pragma unroll
        for (int off = 32; off > 0; off >>= 1) {
            s0 += __shfl_xor(s0, off);
            s1 += __shfl_xor(s1, off);
            s2 += __shfl_xor(s2, off);
            s3 += __shfl_xor(s3, off);
        }
    }

    // In-lane flat softmax (every lane holds all scores).
    const float mx = fmaxf(fmaxf(s0, s1), fmaxf(s2, s3));
    const float e0 = __expf(s0 - mx);
    const float e1 = __expf(s1 - mx);
    const float e2 = __expf(s2 - mx);  // 0 when inactive
    const float e3 = __expf(s3 - mx);  // 0 when inactive
    const float inv = 1.f / (e0 + e1 + e2 + e3);

    f32x4 a0 = e0 * c[0][0] + e1 * c[1][0];
    f32x4 a1 = e0 * c[0][1] + e1 * c[1][1];
    f32x4 a2 = e0 * c[0][2] + e1 * c[1][2];
    if (span > 2) { a0 += e2 * c[2][0]; a1 += e2 * c[2][1]; a2 += e2 * c[2][2]; }
    if (span > 3) { a0 += e3 * c[3][0]; a1 += e3 * c[3][1]; a2 += e3 * c[3][2]; }

    __builtin_nontemporal_store(a0 * inv, &outp[lane]);
    __builtin_nontemporal_store(a1 * inv, &outp[lane + 64]);
    __builtin_nontemporal_store(a2 * inv, &outp[lane + 128]);
}

extern "C" void kernel_launch(void* const* d_in, const int* in_sizes, int n_in,
                              void* d_out, int out_size, void* d_ws, size_t ws_size,
                              hipStream_t stream) {
    const float* ernie      = (const float*)d_in[0];  // (B, S, D) fp32
    const float* emb        = (const float*)d_in[1];  // (VOCAB, D) fp32
    const int*   word_index = (const int*)d_in[2];    // (B, W, 3) int32
    float* out = (float*)d_out;                       // (B, W, D) fp32

    int4* desc = (int4*)d_ws;  // B*W*16 = 307200 bytes of workspace

    prep_kernel<<<B, 64, 0, stream>>>(word_index, desc);

    // One wave per word: B*W = 19200 waves, 4 waves/block -> 4800 blocks.
    const int grid = (B * W) / 4;
    pool_kernel<<<grid, 256, 0, stream>>>(ernie, emb, desc, out);
}

// Round 8
// 219.214 us; speedup vs baseline: 1.0257x; 1.0257x over previous
//
#include <hip/hip_runtime.h>
#include <math.h>

#define VOCAB 32000
#define D 768
#define S 512
#define W 300
#define B 64
#define LMAX 4

typedef float f32x4 __attribute__((ext_vector_type(4)));

// ---------------------------------------------------------------------------
// Kernel 1: prep. Per batch: first-break scan + fill id, then emit one 16B
// descriptor per word so the hot kernel's prologue is a single scalar load.
//   mode 0 (copy-emb):   out = emb[d.x]            (fill path / en >= S)
//   mode 2 (copy-ernie): out = ernie_row[d.x]      (pool with span_eff == 1:
//                        softmax over a singleton is exactly 1.0 -> output
//                        IS the char row, bit-exact vs reference)
//   mode 1 (pool):       softmax-pool, d = {wid, b*S+p0, span_eff, 1}
// ---------------------------------------------------------------------------
__global__ __launch_bounds__(64) void prep_kernel(
    const int* __restrict__ word_index,  // (B, W, 3)
    int4* __restrict__ desc)             // (B, W)
{
    const int b = blockIdx.x;
    const int lane = threadIdx.x;  // 0..63

    int my_first = W;
    for (int w = lane; w < W; w += 64) {
        const int base = (b * W + w) * 3;
        const int st = word_index[base + 1];
        const int en = word_index[base + 2];
        if (en < S && en <= st) my_first = min(my_first, w);
    }
    #pragma unroll
    for (int off = 32; off > 0; off >>= 1)
        my_first = min(my_first, __shfl_xor(my_first, off));
    const int first = my_first;  // butterfly -> all lanes hold the min

    const int fw = min(first, W - 1);
    const int fillid = word_index[(b * W + fw) * 3 + 0];  // same addr all lanes

    for (int w = lane; w < W; w += 64) {
        const int base = (b * W + w) * 3;
        const int wid = word_index[base + 0];
        const int st  = word_index[base + 1];
        const int en  = word_index[base + 2];
        int4 d;
        if (w >= first) {
            d.x = fillid; d.y = 0; d.z = 0; d.w = 0;
        } else if (en >= S) {
            d.x = wid; d.y = 0; d.z = 0; d.w = 0;
        } else {
            const int p0 = min(max(st, 0), S - 1);
            const int span = min(max(en - st, 1), LMAX);
            if (span == 1) {
                d.x = b * S + p0; d.y = 0; d.z = 0; d.w = 2;
            } else {
                d.x = wid;
                d.y = b * S + p0;   // global ernie row of first char
                d.z = span;         // 2..LMAX
                d.w = 1;
            }
        }
        desc[b * W + w] = d;
    }
}

// ---------------------------------------------------------------------------
// Kernel 2: one wave per word, 256-thread blocks (r4's proven launch shape;
// the 1024-thread variant is abandoned after repeated harness failures).
// Single scalar-load prologue (descriptor). Copy modes are pure row copies.
// Pool mode issues all rows up-front (one latency epoch), flat softmax.
// ernie rows (read-once) use nontemporal loads: skip cache allocation, keep
// the cache path clear for the emb gather (r3-vs-r4 isolated this as ~+8%).
// emb loads stay cacheable (reused across words + bench iterations).
// Stores nontemporal (out is write-only).
// ---------------------------------------------------------------------------
__global__ __launch_bounds__(256) void pool_kernel(
    const float* __restrict__ ernie,   // (B, S, D)
    const float* __restrict__ emb,     // (VOCAB, D)
    const int4* __restrict__ desc,     // (B, W)
    float* __restrict__ out)           // (B, W, D)
{
    int gw = (int)((blockIdx.x * blockDim.x + threadIdx.x) >> 6);
    gw = __builtin_amdgcn_readfirstlane(gw);  // wave-uniform -> SGPR
    const int lane = threadIdx.x & 63;

    const int4 d = desc[gw];  // uniform address -> scalar load

    f32x4* __restrict__ outp = (f32x4*)out + (size_t)gw * 192;

    if (d.w == 2) {  // ---- copy-ernie (span==1 pooled word): nt row copy ----
        const f32x4* __restrict__ src = (const f32x4*)ernie + (size_t)d.x * 192;
        __builtin_nontemporal_store(__builtin_nontemporal_load(&src[lane]),       &outp[lane]);
        __builtin_nontemporal_store(__builtin_nontemporal_load(&src[lane + 64]),  &outp[lane + 64]);
        __builtin_nontemporal_store(__builtin_nontemporal_load(&src[lane + 128]), &outp[lane + 128]);
        return;
    }

    if (d.w == 0) {  // ---- copy-emb (fill / out-of-range): cacheable src ----
        const f32x4* __restrict__ src = (const f32x4*)emb + (size_t)d.x * 192;
        __builtin_nontemporal_store(src[lane],       &outp[lane]);
        __builtin_nontemporal_store(src[lane + 64],  &outp[lane + 64]);
        __builtin_nontemporal_store(src[lane + 128], &outp[lane + 128]);
        return;
    }

    // ---- pooling path (span 2..4) ----
    const int span = d.z;  // wave-uniform (SGPR) -> scalar branches
    const f32x4* __restrict__ rp = (const f32x4*)emb + (size_t)d.x * 192;
    const f32x4* __restrict__ cb = (const f32x4*)ernie + (size_t)d.y * 192;

    // Issue everything up-front: one memory-latency epoch.
    f32x4 we0 = rp[lane], we1 = rp[lane + 64], we2 = rp[lane + 128];

    f32x4 c[LMAX][3];  // statically indexed everywhere (no scratch)
    c[0][0] = __builtin_nontemporal_load(&cb[lane]);
    c[0][1] = __builtin_nontemporal_load(&cb[lane + 64]);
    c[0][2] = __builtin_nontemporal_load(&cb[lane + 128]);
    c[1][0] = __builtin_nontemporal_load(&cb[192 + lane]);
    c[1][1] = __builtin_nontemporal_load(&cb[192 + lane + 64]);
    c[1][2] = __builtin_nontemporal_load(&cb[192 + lane + 128]);
    if (span > 2) {
        c[2][0] = __builtin_nontemporal_load(&cb[384 + lane]);
        c[2][1] = __builtin_nontemporal_load(&cb[384 + lane + 64]);
        c[2][2] = __builtin_nontemporal_load(&cb[384 + lane + 128]);
    }
    if (span > 3) {
        c[3][0] = __builtin_nontemporal_load(&cb[576 + lane]);
        c[3][1] = __builtin_nontemporal_load(&cb[576 + lane + 64]);
        c[3][2] = __builtin_nontemporal_load(&cb[576 + lane + 128]);
    }

    // Per-lane partial dots (independent). Inactive slots get -inf so
    // exp() yields exactly 0 (-inf is butterfly-safe: -inf + -inf = -inf).
    f32x4 pv0 = c[0][0] * we0 + c[0][1] * we1 + c[0][2] * we2;
    f32x4 pv1 = c[1][0] * we0 + c[1][1] * we1 + c[1][2] * we2;
    float s0 = pv0.x + pv0.y + pv0.z + pv0.w;
    float s1 = pv1.x + pv1.y + pv1.z + pv1.w;
    float s2 = -INFINITY, s3 = -INFINITY;
    if (span > 2) {
        f32x4 pv = c[2][0] * we0 + c[2][1] * we1 + c[2][2] * we2;
        s2 = pv.x + pv.y + pv.z + pv.w;
    }
    if (span > 3) {
        f32x4 pv = c[3][0] * we0 + c[3][1] * we1 + c[3][2] * we2;
        s3 = pv.x + pv.y + pv.z + pv.w;
    }

    // Batched butterfly: only the live chains (span is scalar -> no diverge).
    if (span == 2) {
        #pragma unroll
        for (int off = 32; off > 0; off >>= 1) {
            s0 += __shfl_xor(s0, off);
            s1 += __shfl_xor(s1, off);
        }
    } else {
        #pragma unroll
        for (int off = 32; off > 0; off >>= 1) {
            s0 += __shfl_xor(s0, off);
            s1 += __shfl_xor(s1, off);
            s2 += __shfl_xor(s2, off);
            s3 += __shfl_xor(s3, off);
        }
    }

    // In-lane flat softmax (every lane holds all scores).
    const float mx = fmaxf(fmaxf(s0, s1), fmaxf(s2, s3));
    const float e0 = __expf(s0 - mx);
    const float e1 = __expf(s1 - mx);
    const float e2 = __expf(s2 - mx);  // 0 when inactive
    const float e3 = __expf(s3 - mx);  // 0 when inactive
    const float inv = 1.f / (e0 + e1 + e2 + e3);

    f32x4 a0 = e0 * c[0][0] + e1 * c[1][0];
    f32x4 a1 = e0 * c[0][1] + e1 * c[1][1];
    f32x4 a2 = e0 * c[0][2] + e1 * c[1][2];
    if (span > 2) { a0 += e2 * c[2][0]; a1 += e2 * c[2][1]; a2 += e2 * c[2][2]; }
    if (span > 3) { a0 += e3 * c[3][0]; a1 += e3 * c[3][1]; a2 += e3 * c[3][2]; }

    __builtin_nontemporal_store(a0 * inv, &outp[lane]);
    __builtin_nontemporal_store(a1 * inv, &outp[lane + 64]);
    __builtin_nontemporal_store(a2 * inv, &outp[lane + 128]);
}

extern "C" void kernel_launch(void* const* d_in, const int* in_sizes, int n_in,
                              void* d_out, int out_size, void* d_ws, size_t ws_size,
                              hipStream_t stream) {
    const float* ernie      = (const float*)d_in[0];  // (B, S, D) fp32
    const float* emb        = (const float*)d_in[1];  // (VOCAB, D) fp32
    const int*   word_index = (const int*)d_in[2];    // (B, W, 3) int32
    float* out = (float*)d_out;                       // (B, W, D) fp32

    int4* desc = (int4*)d_ws;  // B*W*16 = 307200 bytes of workspace

    prep_kernel<<<B, 64, 0, stream>>>(word_index, desc);

    // One wave per word: B*W = 19200 waves, 4 waves/block -> 4800 blocks.
    const int grid = (B * W) / 4;
    pool_kernel<<<grid, 256, 0, stream>>>(ernie, emb, desc, out);
}